// Round 1
// baseline (260.212 us; speedup 1.0000x reference)
//
#include <hip/hip_runtime.h>
#include <math.h>

// Problem constants (from setup_inputs: B=4, S=4096, H=2048, top_k=2048)
#define BB 4
#define SS 4096
#define HH 2048
#define KK 2048
#define ALPHA 0.1f

// Map float bits to order-preserving unsigned key
__device__ __forceinline__ unsigned fkey(float f) {
    unsigned u = __float_as_uint(f);
    return (u & 0x80000000u) ? ~u : (u | 0x80000000u);
}

// ---------------- Kernel 1: logits[b,s] = dot(x[b,s,:], w) ----------------
// One wave per token; 8 float4 loads per lane (64 lanes * 8 * 4 = 2048 floats).
__global__ __launch_bounds__(256) void k_logits(const float* __restrict__ x,
                                                const float* __restrict__ w,
                                                float* __restrict__ logits) {
    int wave = threadIdx.x >> 6;
    int lane = threadIdx.x & 63;
    int t = (blockIdx.x << 2) + wave;          // token index over B*S
    const float4* xv = (const float4*)(x + (size_t)t * HH);
    const float4* wv = (const float4*)w;
    float acc = 0.f;
#pragma unroll
    for (int c = 0; c < HH / 4 / 64; ++c) {    // 8 chunks
        float4 a = xv[c * 64 + lane];
        float4 b = wv[c * 64 + lane];
        acc += a.x * b.x + a.y * b.y + a.z * b.z + a.w * b.w;
    }
#pragma unroll
    for (int off = 32; off > 0; off >>= 1) acc += __shfl_down(acc, off, 64);
    if (lane == 0) logits[t] = acc;
}

// ---------------- Kernel 2: per-row radix-select + scan + writes ----------------
// One block (1024 threads) per batch row. Each thread owns 4 consecutive tokens.
__global__ __launch_bounds__(1024) void k_select(const float* __restrict__ logits,
                                                 float* __restrict__ sel_out,
                                                 float* __restrict__ tgt_out) {
    __shared__ unsigned key[SS];     // 16 KB
    __shared__ unsigned hist[256];
    __shared__ unsigned bc_digit;
    __shared__ unsigned bc_kk;
    __shared__ unsigned scan16[16];

    const int row = blockIdx.x;
    const int tid = threadIdx.x;
    const int lane = tid & 63;
    const int wv = tid >> 6;
    const float* lrow = logits + row * SS;

#pragma unroll
    for (int j = 0; j < 4; ++j) {
        int i = tid * 4 + j;
        key[i] = fkey(lrow[i]);
    }
    __syncthreads();

    // ---- byte-wise radix select for the KK-th largest key ----
    unsigned prefix = 0;
    unsigned kk = KK;                 // rank remaining among current candidates
    for (int p = 3; p >= 0; --p) {
        if (tid < 256) hist[tid] = 0u;
        __syncthreads();              // A
        const int sh = p * 8;
        const unsigned hi = (p == 3) ? 0u : (0xFFFFFFFFu << (sh + 8));
#pragma unroll
        for (int j = 0; j < 4; ++j) {
            unsigned v = key[tid * 4 + j];
            if ((v & hi) == prefix) atomicAdd(&hist[(v >> sh) & 255u], 1u);
        }
        __syncthreads();              // B
        if (tid == 0) {
            unsigned cum = 0;
            for (int d = 255; d >= 0; --d) {
                unsigned h = hist[d];
                if (cum + h >= kk) { bc_digit = (unsigned)d; bc_kk = kk - cum; break; }
                cum += h;
            }
        }
        __syncthreads();              // C
        prefix |= bc_digit << sh;
        kk = bc_kk;
    }
    const unsigned T = prefix;        // KK-th largest key value
    const unsigned kku = kk;          // number of ties (== T) to take, in index order

    // ---- flags + block-wide exclusive prefix scan of (gt, eq) packed 16/16 ----
    unsigned gtf[4], eqf[4];
    unsigned gcnt = 0, ecnt = 0;
#pragma unroll
    for (int j = 0; j < 4; ++j) {
        unsigned v = key[tid * 4 + j];
        gtf[j] = gcnt;
        eqf[j] = ecnt;
        gcnt += (v > T) ? 1u : 0u;
        ecnt += (v == T) ? 1u : 0u;
    }
    unsigned pack = (gcnt << 16) | ecnt;    // totals per field <= 4096, no carry
    unsigned inc = pack;
#pragma unroll
    for (int off = 1; off < 64; off <<= 1) {
        unsigned n = __shfl_up(inc, off, 64);
        if (lane >= off) inc += n;
    }
    unsigned wave_excl = inc - pack;
    if (lane == 63) scan16[wv] = inc;
    __syncthreads();
    if (tid == 0) {
        unsigned run = 0;
        for (int w2 = 0; w2 < 16; ++w2) { unsigned t2 = scan16[w2]; scan16[w2] = run; run += t2; }
    }
    __syncthreads();
    unsigned base = wave_excl + scan16[wv];
    unsigned gbase = base >> 16;
    unsigned ebase = base & 0xFFFFu;

#pragma unroll
    for (int j = 0; j < 4; ++j) {
        int i = tid * 4 + j;
        unsigned v = key[i];
        unsigned eg = gbase + gtf[j];                 // # gt before i
        unsigned ee = ebase + eqf[j];                 // # eq before i
        bool seld = (v > T) || ((v == T) && (ee < kku));
        tgt_out[row * SS + i] = seld ? 1.0f : 0.0f;
        if (seld) {
            unsigned pos = eg + (ee < kku ? ee : kku);  // ascending-index position
            sel_out[row * KK + pos] = (float)i;
        }
    }
}

// ---------------- Kernel 3: gather + scale ----------------
// One block per selected token; 256 threads * 2 float4 = 2048 floats.
__global__ __launch_bounds__(256) void k_gather(const float* __restrict__ x,
                                                const float* __restrict__ logits,
                                                const float* __restrict__ sel,
                                                float* __restrict__ out) {
    int b = blockIdx.x >> 11;           // / KK
    int j = blockIdx.x & (KK - 1);
    int s = (int)sel[b * KK + j];
    float lg = logits[b * SS + s];
    float w = ALPHA / (1.0f + expf(-lg));   // alpha * sigmoid(logit)
    const float4* src = (const float4*)(x + ((size_t)(b * SS + s)) * HH);
    float4* dst = (float4*)(out + ((size_t)(b * KK + j)) * HH);
#pragma unroll
    for (int c = 0; c < HH / 4 / 256; ++c) {  // 2 iterations
        float4 a = src[c * 256 + threadIdx.x];
        dst[c * 256 + threadIdx.x] = make_float4(a.x * w, a.y * w, a.z * w, a.w * w);
    }
}

extern "C" void kernel_launch(void* const* d_in, const int* in_sizes, int n_in,
                              void* d_out, int out_size, void* d_ws, size_t ws_size,
                              hipStream_t stream) {
    const float* x = (const float*)d_in[0];
    const float* w = (const float*)d_in[1];
    float* out = (float*)d_out;

    // d_out layout (floats): out [B*K*H] | sel [B*K] | targets [B*S]
    float* sel_out = out + (size_t)BB * KK * HH;
    float* tgt_out = sel_out + (size_t)BB * KK;

    // workspace: logits B*S floats (64 KB)
    float* logits = (float*)d_ws;

    k_logits<<<BB * SS / 4, 256, 0, stream>>>(x, w, logits);
    k_select<<<BB, 1024, 0, stream>>>(logits, sel_out, tgt_out);
    k_gather<<<BB * KK, 256, 0, stream>>>(x, logits, sel_out, out);
}

// Round 2
// 227.941 us; speedup vs baseline: 1.1416x; 1.1416x over previous
//
#include <hip/hip_runtime.h>
#include <math.h>

// Problem constants (from setup_inputs: B=4, S=4096, H=2048, top_k=2048)
#define BB 4
#define SS 4096
#define HH 2048
#define KK 2048
#define ALPHA 0.1f

// Map float bits to order-preserving unsigned key
__device__ __forceinline__ unsigned fkey(float f) {
    unsigned u = __float_as_uint(f);
    return (u & 0x80000000u) ? ~u : (u | 0x80000000u);
}

// ---------------- Kernel 1: logits[b,s] = dot(x[b,s,:], w) ----------------
// One wave per token; 8 float4 loads per lane (64 lanes * 8 * 4 = 2048 floats).
__global__ __launch_bounds__(256) void k_logits(const float* __restrict__ x,
                                                const float* __restrict__ w,
                                                float* __restrict__ logits) {
    int wave = threadIdx.x >> 6;
    int lane = threadIdx.x & 63;
    int t = (blockIdx.x << 2) + wave;          // token index over B*S
    const float4* xv = (const float4*)(x + (size_t)t * HH);
    const float4* wv = (const float4*)w;
    float acc = 0.f;
#pragma unroll
    for (int c = 0; c < HH / 4 / 64; ++c) {    // 8 chunks
        float4 a = xv[c * 64 + lane];
        float4 b = wv[c * 64 + lane];
        acc += a.x * b.x + a.y * b.y + a.z * b.z + a.w * b.w;
    }
#pragma unroll
    for (int off = 32; off > 0; off >>= 1) acc += __shfl_down(acc, off, 64);
    if (lane == 0) logits[t] = acc;
}

// ---------------- Kernel 2: per-row radix-select + scan + writes ----------------
// One block (1024 threads) per batch row. Each thread owns 4 consecutive tokens.
__global__ __launch_bounds__(1024) void k_select(const float* __restrict__ logits,
                                                 float* __restrict__ sel_out,
                                                 float* __restrict__ tgt_out) {
    __shared__ unsigned key[SS];     // 16 KB
    __shared__ unsigned hist[256];
    __shared__ unsigned bc_digit;
    __shared__ unsigned bc_kk;
    __shared__ unsigned scan16[16];

    const int row = blockIdx.x;
    const int tid = threadIdx.x;
    const int lane = tid & 63;
    const int wv = tid >> 6;
    const float* lrow = logits + row * SS;

#pragma unroll
    for (int j = 0; j < 4; ++j) {
        int i = tid * 4 + j;
        key[i] = fkey(lrow[i]);
    }
    __syncthreads();

    // ---- byte-wise radix select for the KK-th largest key ----
    unsigned prefix = 0;
    unsigned kk = KK;                 // rank remaining among current candidates
    for (int p = 3; p >= 0; --p) {
        if (tid < 256) hist[tid] = 0u;
        __syncthreads();              // A
        const int sh = p * 8;
        const unsigned hi = (p == 3) ? 0u : (0xFFFFFFFFu << (sh + 8));
#pragma unroll
        for (int j = 0; j < 4; ++j) {
            unsigned v = key[tid * 4 + j];
            if ((v & hi) == prefix) atomicAdd(&hist[(v >> sh) & 255u], 1u);
        }
        __syncthreads();              // B
        // Parallel digit selection: wave 0 does a 64-lane Kogge-Stone suffix
        // scan over per-lane sums of 4 bins each, then each lane checks its
        // 4 digits (descending) for the kk-crossing. Replaces the former
        // 256-iteration serial walk (was ~10-15us over 4 passes).
        if (tid < 64) {
            unsigned h0 = hist[tid * 4 + 0];
            unsigned h1 = hist[tid * 4 + 1];
            unsigned h2 = hist[tid * 4 + 2];
            unsigned h3 = hist[tid * 4 + 3];
            unsigned lanesum = h0 + h1 + h2 + h3;
            unsigned inc = lanesum;
#pragma unroll
            for (int off = 1; off < 64; off <<= 1) {
                unsigned n = __shfl_down(inc, off, 64);
                if (tid + off < 64) inc += n;
            }
            unsigned cumHigher = inc - lanesum;   // count of keys with digit >= 4*(tid+1)
            // digits descending: 4*tid+3, +2, +1, +0
            unsigned hv[4] = {h3, h2, h1, h0};
#pragma unroll
            for (int j = 0; j < 4; ++j) {
                unsigned d = tid * 4 + (3 - j);
                unsigned h = hv[j];
                if (cumHigher < kk && cumHigher + h >= kk) {
                    bc_digit = d;
                    bc_kk = kk - cumHigher;
                }
                cumHigher += h;
            }
        }
        __syncthreads();              // C
        prefix |= bc_digit << sh;
        kk = bc_kk;
    }
    const unsigned T = prefix;        // KK-th largest key value
    const unsigned kku = kk;          // number of ties (== T) to take, in index order

    // ---- flags + block-wide exclusive prefix scan of (gt, eq) packed 16/16 ----
    unsigned gtf[4], eqf[4];
    unsigned gcnt = 0, ecnt = 0;
#pragma unroll
    for (int j = 0; j < 4; ++j) {
        unsigned v = key[tid * 4 + j];
        gtf[j] = gcnt;
        eqf[j] = ecnt;
        gcnt += (v > T) ? 1u : 0u;
        ecnt += (v == T) ? 1u : 0u;
    }
    unsigned pack = (gcnt << 16) | ecnt;    // totals per field <= 4096, no carry
    unsigned inc = pack;
#pragma unroll
    for (int off = 1; off < 64; off <<= 1) {
        unsigned n = __shfl_up(inc, off, 64);
        if (lane >= off) inc += n;
    }
    unsigned wave_excl = inc - pack;
    if (lane == 63) scan16[wv] = inc;
    __syncthreads();
    if (tid == 0) {
        unsigned run = 0;
        for (int w2 = 0; w2 < 16; ++w2) { unsigned t2 = scan16[w2]; scan16[w2] = run; run += t2; }
    }
    __syncthreads();
    unsigned base = wave_excl + scan16[wv];
    unsigned gbase = base >> 16;
    unsigned ebase = base & 0xFFFFu;

#pragma unroll
    for (int j = 0; j < 4; ++j) {
        int i = tid * 4 + j;
        unsigned v = key[i];
        unsigned eg = gbase + gtf[j];                 // # gt before i
        unsigned ee = ebase + eqf[j];                 // # eq before i
        bool seld = (v > T) || ((v == T) && (ee < kku));
        tgt_out[row * SS + i] = seld ? 1.0f : 0.0f;
        if (seld) {
            unsigned pos = eg + (ee < kku ? ee : kku);  // ascending-index position
            sel_out[row * KK + pos] = (float)i;
        }
    }
}

// ---------------- Kernel 3: gather + scale ----------------
// One block per selected token; 256 threads * 2 float4 = 2048 floats.
__global__ __launch_bounds__(256) void k_gather(const float* __restrict__ x,
                                                const float* __restrict__ logits,
                                                const float* __restrict__ sel,
                                                float* __restrict__ out) {
    int b = blockIdx.x >> 11;           // / KK
    int j = blockIdx.x & (KK - 1);
    int s = (int)sel[b * KK + j];
    float lg = logits[b * SS + s];
    float w = ALPHA / (1.0f + expf(-lg));   // alpha * sigmoid(logit)
    const float4* src = (const float4*)(x + ((size_t)(b * SS + s)) * HH);
    float4* dst = (float4*)(out + ((size_t)(b * KK + j)) * HH);
#pragma unroll
    for (int c = 0; c < HH / 4 / 256; ++c) {  // 2 iterations
        float4 a = src[c * 256 + threadIdx.x];
        dst[c * 256 + threadIdx.x] = make_float4(a.x * w, a.y * w, a.z * w, a.w * w);
    }
}

extern "C" void kernel_launch(void* const* d_in, const int* in_sizes, int n_in,
                              void* d_out, int out_size, void* d_ws, size_t ws_size,
                              hipStream_t stream) {
    const float* x = (const float*)d_in[0];
    const float* w = (const float*)d_in[1];
    float* out = (float*)d_out;

    // d_out layout (floats): out [B*K*H] | sel [B*K] | targets [B*S]
    float* sel_out = out + (size_t)BB * KK * HH;
    float* tgt_out = sel_out + (size_t)BB * KK;

    // workspace: logits B*S floats (64 KB)
    float* logits = (float*)d_ws;

    k_logits<<<BB * SS / 4, 256, 0, stream>>>(x, w, logits);
    k_select<<<BB, 1024, 0, stream>>>(logits, sel_out, tgt_out);
    k_gather<<<BB * KK, 256, 0, stream>>>(x, logits, sel_out, out);
}

// Round 4
// 227.632 us; speedup vs baseline: 1.1431x; 1.0014x over previous
//
#include <hip/hip_runtime.h>
#include <math.h>

// Problem constants (from setup_inputs: B=4, S=4096, H=2048, top_k=2048)
#define BB 4
#define SS 4096
#define HH 2048
#define KK 2048
#define ALPHA 0.1f

// Native clang vector type — required by __builtin_nontemporal_store
// (HIP's float4 is a class and is rejected by the builtin).
typedef float f32x4 __attribute__((ext_vector_type(4)));

// Map float bits to order-preserving unsigned key
__device__ __forceinline__ unsigned fkey(float f) {
    unsigned u = __float_as_uint(f);
    return (u & 0x80000000u) ? ~u : (u | 0x80000000u);
}

// ---------------- Kernel 1: logits[b,s] = dot(x[b,s,:], w) ----------------
// One wave per token; 8 float4 loads per lane (64 lanes * 8 * 4 = 2048 floats).
__global__ __launch_bounds__(256) void k_logits(const float* __restrict__ x,
                                                const float* __restrict__ w,
                                                float* __restrict__ logits) {
    int wave = threadIdx.x >> 6;
    int lane = threadIdx.x & 63;
    int t = (blockIdx.x << 2) + wave;          // token index over B*S
    const float4* xv = (const float4*)(x + (size_t)t * HH);
    const float4* wv = (const float4*)w;
    float acc = 0.f;
#pragma unroll
    for (int c = 0; c < HH / 4 / 64; ++c) {    // 8 chunks
        float4 a = xv[c * 64 + lane];
        float4 b = wv[c * 64 + lane];
        acc += a.x * b.x + a.y * b.y + a.z * b.z + a.w * b.w;
    }
#pragma unroll
    for (int off = 32; off > 0; off >>= 1) acc += __shfl_down(acc, off, 64);
    if (lane == 0) logits[t] = acc;
}

// ---------------- Kernel 2: per-row radix-select + scan + writes ----------------
// One block (1024 threads) per batch row. Each thread owns 4 consecutive tokens.
__global__ __launch_bounds__(1024) void k_select(const float* __restrict__ logits,
                                                 float* __restrict__ sel_out,
                                                 float* __restrict__ tgt_out,
                                                 float* __restrict__ wtop) {
    __shared__ unsigned key[SS];     // 16 KB
    __shared__ unsigned hist[256];
    __shared__ unsigned bc_digit;
    __shared__ unsigned bc_kk;
    __shared__ unsigned scan16[16];

    const int row = blockIdx.x;
    const int tid = threadIdx.x;
    const int lane = tid & 63;
    const int wv = tid >> 6;

    // vectorized logits load: 1024 threads x float4 covers 4096 floats
    const float4* lrow4 = (const float4*)(logits + row * SS);
    float4 lv = lrow4[tid];
    float lf[4] = {lv.x, lv.y, lv.z, lv.w};
    key[tid * 4 + 0] = fkey(lv.x);
    key[tid * 4 + 1] = fkey(lv.y);
    key[tid * 4 + 2] = fkey(lv.z);
    key[tid * 4 + 3] = fkey(lv.w);
    __syncthreads();

    // ---- byte-wise radix select for the KK-th largest key ----
    unsigned prefix = 0;
    unsigned kk = KK;                 // rank remaining among current candidates
    for (int p = 3; p >= 0; --p) {
        if (tid < 256) hist[tid] = 0u;
        __syncthreads();              // A
        const int sh = p * 8;
        const unsigned hi = (p == 3) ? 0u : (0xFFFFFFFFu << (sh + 8));
#pragma unroll
        for (int j = 0; j < 4; ++j) {
            unsigned v = key[tid * 4 + j];
            if ((v & hi) == prefix) atomicAdd(&hist[(v >> sh) & 255u], 1u);
        }
        __syncthreads();              // B
        // Parallel digit selection: wave 0 does a 64-lane Kogge-Stone suffix
        // scan over per-lane sums of 4 bins each, then each lane checks its
        // 4 digits (descending) for the kk-crossing.
        if (tid < 64) {
            unsigned h0 = hist[tid * 4 + 0];
            unsigned h1 = hist[tid * 4 + 1];
            unsigned h2 = hist[tid * 4 + 2];
            unsigned h3 = hist[tid * 4 + 3];
            unsigned lanesum = h0 + h1 + h2 + h3;
            unsigned inc = lanesum;
#pragma unroll
            for (int off = 1; off < 64; off <<= 1) {
                unsigned n = __shfl_down(inc, off, 64);
                if (tid + off < 64) inc += n;
            }
            unsigned cumHigher = inc - lanesum;   // keys with digit >= 4*(tid+1)
            unsigned hv[4] = {h3, h2, h1, h0};
#pragma unroll
            for (int j = 0; j < 4; ++j) {
                unsigned d = tid * 4 + (3 - j);
                unsigned h = hv[j];
                if (cumHigher < kk && cumHigher + h >= kk) {
                    bc_digit = d;
                    bc_kk = kk - cumHigher;
                }
                cumHigher += h;
            }
        }
        __syncthreads();              // C
        prefix |= bc_digit << sh;
        kk = bc_kk;
    }
    const unsigned T = prefix;        // KK-th largest key value
    const unsigned kku = kk;          // number of ties (== T) to take, in index order

    // ---- flags + block-wide exclusive prefix scan of (gt, eq) packed 16/16 ----
    unsigned gtf[4], eqf[4];
    unsigned gcnt = 0, ecnt = 0;
#pragma unroll
    for (int j = 0; j < 4; ++j) {
        unsigned v = key[tid * 4 + j];
        gtf[j] = gcnt;
        eqf[j] = ecnt;
        gcnt += (v > T) ? 1u : 0u;
        ecnt += (v == T) ? 1u : 0u;
    }
    unsigned pack = (gcnt << 16) | ecnt;    // totals per field <= 4096, no carry
    unsigned inc = pack;
#pragma unroll
    for (int off = 1; off < 64; off <<= 1) {
        unsigned n = __shfl_up(inc, off, 64);
        if (lane >= off) inc += n;
    }
    unsigned wave_excl = inc - pack;
    if (lane == 63) scan16[wv] = inc;
    __syncthreads();
    if (tid == 0) {
        unsigned run = 0;
        for (int w2 = 0; w2 < 16; ++w2) { unsigned t2 = scan16[w2]; scan16[w2] = run; run += t2; }
    }
    __syncthreads();
    unsigned base = wave_excl + scan16[wv];
    unsigned gbase = base >> 16;
    unsigned ebase = base & 0xFFFFu;

#pragma unroll
    for (int j = 0; j < 4; ++j) {
        int i = tid * 4 + j;
        unsigned v = key[i];
        unsigned eg = gbase + gtf[j];                 // # gt before i
        unsigned ee = ebase + eqf[j];                 // # eq before i
        bool seld = (v > T) || ((v == T) && (ee < kku));
        tgt_out[row * SS + i] = seld ? 1.0f : 0.0f;
        if (seld) {
            unsigned pos = eg + (ee < kku ? ee : kku);  // ascending-index position
            sel_out[row * KK + pos] = (float)i;
            wtop[row * KK + pos] = ALPHA / (1.0f + expf(-lf[j]));
        }
    }
}

// ---------------- Kernel 3: gather + scale ----------------
// Two tokens per block (more loads in flight); 256 threads * 2 float4 each.
// Nontemporal stores: out is streamed, keep x resident in L2/L3.
__global__ __launch_bounds__(256) void k_gather(const float* __restrict__ x,
                                                const float* __restrict__ sel,
                                                const float* __restrict__ wt,
                                                float* __restrict__ out) {
    int blk = blockIdx.x;               // 4096 blocks
    int b = blk >> 10;                  // / 1024
    int j0 = (blk & 1023) * 2;
    int tid = threadIdx.x;
#pragma unroll
    for (int t = 0; t < 2; ++t) {
        int j = j0 + t;
        int s = (int)sel[b * KK + j];
        float w = wt[b * KK + j];
        const f32x4* src = (const f32x4*)(x + ((size_t)(b * SS + s)) * HH);
        f32x4* dst = (f32x4*)(out + ((size_t)(b * KK + j)) * HH);
#pragma unroll
        for (int c = 0; c < 2; ++c) {
            f32x4 a = src[c * 256 + tid];
            f32x4 r = a * w;
            __builtin_nontemporal_store(r, &dst[c * 256 + tid]);
        }
    }
}

extern "C" void kernel_launch(void* const* d_in, const int* in_sizes, int n_in,
                              void* d_out, int out_size, void* d_ws, size_t ws_size,
                              hipStream_t stream) {
    const float* x = (const float*)d_in[0];
    const float* w = (const float*)d_in[1];
    float* out = (float*)d_out;

    // d_out layout (floats): out [B*K*H] | sel [B*K] | targets [B*S]
    float* sel_out = out + (size_t)BB * KK * HH;
    float* tgt_out = sel_out + (size_t)BB * KK;

    // workspace: logits B*S floats (64 KB) | wtop B*K floats (32 KB)
    float* logits = (float*)d_ws;
    float* wtop = logits + (size_t)BB * SS;

    k_logits<<<BB * SS / 4, 256, 0, stream>>>(x, w, logits);
    k_select<<<BB, 1024, 0, stream>>>(logits, sel_out, tgt_out, wtop);
    k_gather<<<BB * KK / 2, 256, 0, stream>>>(x, sel_out, wtop, out);
}